// Round 6
// baseline (87.654 us; speedup 1.0000x reference)
//
#include <hip/hip_runtime.h>

// Problem constants (from reference)
#define B_    8
#define H_    512
#define W_    512
#define KS_   3
#define KK_   9
#define COUT_ 3
#define HO_   510
#define WO_   510

// Tiling
#define TR_   8      // output rows per tile
#define TC_   128    // output cols per tile
#define XOFF_ 7      // staged halo (+1 for floor) on each side
#define XR_   24     // staged x rows: TR_ + 2(kh) + 2*XOFF_ ... covers dy in (-7, 7)
#define XC_   144    // staged x cols: TC_ + 2(kw) + 2*XOFF_ + 2
#define XCP_  145    // padded LDS row stride (odd -> bank spread)

typedef float f2 __attribute__((ext_vector_type(2)));

__device__ __forceinline__ int iclamp(int v, int lo, int hi) {
    return v < lo ? lo : (v > hi ? hi : v);
}

__global__ __launch_bounds__(256) void dcn_fwd_kernel(
    const float* __restrict__ x,       // [B,1,H,W]
    const float* __restrict__ offset,  // [B,2*KK,HO,WO]
    const float* __restrict__ mask,    // [B,KK,HO,WO]
    const float* __restrict__ weight,  // [COUT,1,KS,KS]
    const float* __restrict__ bias,    // [COUT]
    float* __restrict__ out)           // [B,COUT,HO,WO]
{
    __shared__ float sx[XR_ * XCP_];

    const int bid = blockIdx.x;            // 8 * 64 * 4 = 2048 blocks
    const int wt  = bid & 3;               // wo tile 0..3
    const int ht  = (bid >> 2) & 63;       // ho tile 0..63
    const int b   = bid >> 8;              // batch 0..7

    const int ho0  = ht * TR_;
    const int wo_t = wt * TC_;
    const int XR0  = ho0  - XOFF_;
    const int XC0  = wo_t - XOFF_;

    const float* xb = x + (size_t)b * (H_ * W_);

    // ---- stage x window into LDS (clamped-replicate borders) ----
    for (int i = threadIdx.x; i < XR_ * XC_; i += 256) {
        const int r = i / XC_;
        const int c = i - r * XC_;
        const int sr = iclamp(XR0 + r, 0, H_ - 1);
        const int sc = iclamp(XC0 + c, 0, W_ - 1);
        sx[r * XCP_ + c] = xb[sr * W_ + sc];
    }
    __syncthreads();

    // ---- per-thread output mapping: 2 wo px  x  rows {r, r+4} ----
    const int c = threadIdx.x & 63;
    const int r = threadIdx.x >> 6;        // 0..3, wave-uniform
    int wo0 = wo_t + 2 * c;
    if (wo0 > WO_ - 2) wo0 = WO_ - 2;      // duplicate px at right edge (benign)

    const size_t planeO = (size_t)HO_ * WO_;

    // weights/bias: uniform addresses -> scalar broadcast loads
    float w0[KK_], w1[KK_], w2[KK_];
    #pragma unroll
    for (int k = 0; k < KK_; ++k) {
        w0[k] = weight[0 * KK_ + k];
        w1[k] = weight[1 * KK_ + k];
        w2[k] = weight[2 * KK_ + k];
    }
    const float b0 = bias[0], b1 = bias[1], b2 = bias[2];

    float acc[2][3][2];
    #pragma unroll
    for (int a = 0; a < 2; ++a)
        #pragma unroll
        for (int o = 0; o < 3; ++o)
            acc[a][o][0] = acc[a][o][1] = 0.f;

    #pragma unroll
    for (int rr = 0; rr < 2; ++rr) {
        const int ho = ho0 + r + rr * 4;   // wave-uniform row
        if (ho >= HO_) continue;

        const size_t pix  = (size_t)ho * WO_ + (size_t)wo0;   // even -> 8B aligned
        const float* offb = offset + (size_t)b * (2 * KK_) * planeO + pix;
        const float* mb   = mask   + (size_t)b * KK_ * planeO       + pix;

        #pragma unroll
        for (int kk = 0; kk < KK_; ++kk) {
            const float* dyp = offb + (size_t)(2 * kk) * planeO;
            const float* dxp = dyp + planeO;
            const float* mp  = mb + (size_t)kk * planeO;

            const f2 dyv = *(const f2*)dyp;
            const f2 dxv = *(const f2*)dxp;
            const f2 mv  = *(const f2*)mp;

            const float baseY  = (float)(ho  + kk / KS_);
            const float baseX0 = (float)(wo0 + kk % KS_);

            #pragma unroll
            for (int p = 0; p < 2; ++p) {
                const float py = baseY + dyv[p];
                const float px = baseX0 + (float)p + dxv[p];

                const float y0f = floorf(py);
                const float x0f = floorf(px);
                const float ly  = py - y0f;
                const float lx  = px - x0f;
                const float y1f = y0f + 1.0f;
                const float x1f = x0f + 1.0f;

                // validity on UNCLIPPED float corner coords (reference semantics)
                const float vy0 = (y0f >= 0.0f && y0f <= (float)(H_ - 1)) ? 1.0f : 0.0f;
                const float vy1 = (y1f >= 0.0f && y1f <= (float)(H_ - 1)) ? 1.0f : 0.0f;
                const float vx0 = (x0f >= 0.0f && x0f <= (float)(W_ - 1)) ? 1.0f : 0.0f;
                const float vx1 = (x1f >= 0.0f && x1f <= (float)(W_ - 1)) ? 1.0f : 0.0f;

                const int yi0 = iclamp((int)y0f, 0, H_ - 1);
                const int yi1 = iclamp((int)y1f, 0, H_ - 1);
                const int xi0 = iclamp((int)x0f, 0, W_ - 1);
                const int xi1 = iclamp((int)x1f, 0, W_ - 1);

                const int lr0 = yi0 - XR0, lr1 = yi1 - XR0;
                const int lc0 = xi0 - XC0, lc1 = xi1 - XC0;
                const bool inT = (lr0 >= 0) & (lr1 < XR_) & (lc0 >= 0) & (lc1 < XC_);

                float v00, v01, v10, v11;
                if (inT) {
                    // LDS sampling (clamped-replicate window == global clamped read)
                    v00 = sx[lr0 * XCP_ + lc0];
                    v01 = sx[lr0 * XCP_ + lc1];
                    v10 = sx[lr1 * XCP_ + lc0];
                    v11 = sx[lr1 * XCP_ + lc1];
                } else {
                    // rare fallback: offset beyond halo
                    v00 = xb[yi0 * W_ + xi0];
                    v01 = xb[yi0 * W_ + xi1];
                    v10 = xb[yi1 * W_ + xi0];
                    v11 = xb[yi1 * W_ + xi1];
                }
                v00 *= (vy0 * vx0);
                v01 *= (vy0 * vx1);
                v10 *= (vy1 * vx0);
                v11 *= (vy1 * vx1);

                const float val = v00 * (1.0f - ly) * (1.0f - lx)
                                + v01 * (1.0f - ly) * lx
                                + v10 * ly * (1.0f - lx)
                                + v11 * ly * lx;

                const float s = val * mv[p];
                acc[rr][0][p] = fmaf(w0[kk], s, acc[rr][0][p]);
                acc[rr][1][p] = fmaf(w1[kk], s, acc[rr][1][p]);
                acc[rr][2][p] = fmaf(w2[kk], s, acc[rr][2][p]);
            }
        }
    }

    // ---- stores ----
    #pragma unroll
    for (int rr = 0; rr < 2; ++rr) {
        const int ho = ho0 + r + rr * 4;
        if (ho >= HO_) continue;
        const size_t obase = (size_t)b * COUT_ * planeO + (size_t)ho * WO_ + (size_t)wo0;
        f2 o0 = {acc[rr][0][0] + b0, acc[rr][0][1] + b0};
        f2 o1 = {acc[rr][1][0] + b1, acc[rr][1][1] + b1};
        f2 o2 = {acc[rr][2][0] + b2, acc[rr][2][1] + b2};
        *(f2*)(out + obase)              = o0;
        *(f2*)(out + obase + planeO)     = o1;
        *(f2*)(out + obase + 2 * planeO) = o2;
    }
}

extern "C" void kernel_launch(void* const* d_in, const int* in_sizes, int n_in,
                              void* d_out, int out_size, void* d_ws, size_t ws_size,
                              hipStream_t stream) {
    const float* x      = (const float*)d_in[0];
    const float* offset = (const float*)d_in[1];
    const float* mask   = (const float*)d_in[2];
    const float* weight = (const float*)d_in[3];
    const float* bias   = (const float*)d_in[4];
    float* out = (float*)d_out;

    const int grid = B_ * (HO_ / TR_ + ((HO_ % TR_) ? 1 : 0)) * (WO_ / TC_ + ((WO_ % TC_) ? 1 : 0)); // 8*64*4 = 2048
    dcn_fwd_kernel<<<grid, 256, 0, stream>>>(x, offset, mask, weight, bias, out);
}